// Round 15
// baseline (267.225 us; speedup 1.0000x reference)
//
#include <hip/hip_runtime.h>
#include <hip/hip_cooperative_groups.h>

namespace cg = cooperative_groups;

#define B 8
#define N 4096
#define NITER 4
#define NBLK 256          // one block per CU -> cooperative co-residency
#define TPB 1024          // 16 waves/block, 4 waves/SIMD
#define CPB 16            // columns owned per block

// All 4 iterations in ONE cooperative kernel; P STREAMED each iteration.
// Structure = round-4's verified skeleton (block owns 16 cols x all 4096 b;
// wave w: b in [w*256,+256); lane: cc=l&15 -> col, q=l>>4 -> 64 b) but with
// NO p[64] register array (rounds 4/9: allocator caps at 64 VGPR for
// TPB=1024 and scratch-spills any big array; streamed form needs ~50 VGPR).
// vs round 12 (9 dispatches/call): deletes 8 kernel boundaries and the
// partial->combine global round-trip; adds 3 grid.sync()s. Single ~110us
// dispatch ALSO surfaces step-phase counters above the 41us poison fills
// (never measured so far): FETCH ~64-100MB => L3 retains P, latency-bound;
// FETCH ~256MB => P re-streamed from HBM each iter.
__global__ __launch_bounds__(TPB) void fused_kernel(
        const float* __restrict__ P,
        const float* __restrict__ maskT,  // [N][B] seed mask, transposed
        float* __restrict__ bufA,         // [N][B] pred state (starts = predsT)
        float* __restrict__ bufB,         // [N][B] ping-pong partner
        float* __restrict__ out)          // [B][N] final output
{
    cg::grid_group grid = cg::this_grid();

    const int tid   = threadIdx.x;
    const int wave  = tid >> 6;          // 0..15
    const int lane  = tid & 63;
    const int cc    = lane & 15;         // col within block
    const int q     = lane >> 4;         // 0..3
    // bijective XCD swizzle: 32 consecutive colgroups per XCD
    const int colgroup = (blockIdx.x & 7) * 32 + (blockIdx.x >> 3);
    const int c0    = colgroup * CPB;
    const int c     = c0 + cc;
    const int bbase = wave * 256 + q * 64;

    const float* Pp = P + (size_t)bbase * N + c;

    __shared__ float redbuf[16][16][B];   // [wave][col][batch] = 8 KB

    const float* src = bufA;
    float* dst = bufB;

    for (int it = 0; it < NITER; ++it) {
        float prod[B];
#pragma unroll
        for (int i = 0; i < B; ++i) prod[i] = 1.0f;

        const float* sp = src + (size_t)bbase * B;

#pragma unroll 4
        for (int j = 0; j < 64; ++j) {
            const float pj = Pp[(size_t)j * N];                              // 64B/16 lanes, coalesced
            const float4 lo = *reinterpret_cast<const float4*>(sp + j * B);  // q-group-uniform, L1/L2-hot
            const float4 hi = *reinterpret_cast<const float4*>(sp + j * B + 4);
            prod[0] *= fmaf(-pj, lo.x, 1.0f);
            prod[1] *= fmaf(-pj, lo.y, 1.0f);
            prod[2] *= fmaf(-pj, lo.z, 1.0f);
            prod[3] *= fmaf(-pj, lo.w, 1.0f);
            prod[4] *= fmaf(-pj, hi.x, 1.0f);
            prod[5] *= fmaf(-pj, hi.y, 1.0f);
            prod[6] *= fmaf(-pj, hi.z, 1.0f);
            prod[7] *= fmaf(-pj, hi.w, 1.0f);
        }

        // product across the 4 q-groups (lanes l, l^16, l^32, l^48 share a column)
#pragma unroll
        for (int i = 0; i < B; ++i) {
            prod[i] *= __shfl_xor(prod[i], 16);
            prod[i] *= __shfl_xor(prod[i], 32);
        }
        if (lane < 16) {
#pragma unroll
            for (int i = 0; i < B; ++i) redbuf[wave][cc][i] = prod[i];
        }
        __syncthreads();

        // wave 0: product across 16 waves; 128 (col,batch) pairs, 2 per lane
        if (wave == 0) {
#pragma unroll
            for (int rep = 0; rep < 2; ++rep) {
                const int pidx = lane + rep * 64;
                const int rc = pidx >> 3;    // col 0..15
                const int ri = pidx & 7;     // batch 0..7
                float r = 1.0f;
#pragma unroll
                for (int w = 0; w < 16; ++w) r *= redbuf[w][rc][ri];
                float v = 1.0f - r;
                if (maskT[(size_t)(c0 + rc) * B + ri] != 0.0f) v = 1.0f;
                if (it < NITER - 1) dst[(size_t)(c0 + rc) * B + ri] = v;
                else                out[(size_t)ri * N + (c0 + rc)] = v;   // final row-major
            }
        }
        if (it < NITER - 1) {
            grid.sync();            // makes dst visible grid-wide; also orders
                                    // redbuf reuse (wave0 reads precede sync)
            const float* t = src; src = dst; dst = (float*)t;
        }
    }
}

// Transpose preds into [N][B] + scatter seed mask (maskT pre-zeroed by memset).
__global__ void prep_kernel(const float* __restrict__ preds,
                            const int* __restrict__ seed_idx, int nseeds,
                            float* __restrict__ predsT, float* __restrict__ maskT) {
    const int t = blockIdx.x * blockDim.x + threadIdx.x;   // t = i*N + n
    if (t < B * N) {
        const int i = t / N;
        const int n = t % N;
        predsT[(size_t)n * B + i] = preds[t];
    }
    if (t < nseeds) {
        const int b = seed_idx[2 * t + 0];
        const int n = seed_idx[2 * t + 1];
        maskT[(size_t)n * B + b] = 1.0f;
    }
}

extern "C" void kernel_launch(void* const* d_in, const int* in_sizes, int n_in,
                              void* d_out, int out_size, void* d_ws, size_t ws_size,
                              hipStream_t stream) {
    const float* preds    = (const float*)d_in[0];   // [B, N]
    const float* P        = (const float*)d_in[1];   // [N, N]
    const int*   seed_idx = (const int*)d_in[2];     // [NSEEDS, 2]
    const int nseeds = in_sizes[2] / 2;

    float* out   = (float*)d_out;                    // [B, N]
    float* bufA  = (float*)d_ws;                     // 128 KB each
    float* bufB  = bufA + (size_t)B * N;
    float* maskT = bufB + (size_t)B * N;

    hipMemsetAsync(maskT, 0, (size_t)B * N * sizeof(float), stream);
    prep_kernel<<<dim3((B * N) / 256), 256, 0, stream>>>(preds, seed_idx, nseeds, bufA, maskT);

    void* args[] = {(void*)&P, (void*)&maskT, (void*)&bufA, (void*)&bufB, (void*)&out};
    hipLaunchCooperativeKernel(reinterpret_cast<void*>(fused_kernel),
                               dim3(NBLK), dim3(TPB), args, 0, stream);
}

// Round 17
// 169.627 us; speedup vs baseline: 1.5754x; 1.5754x over previous
//
#include <hip/hip_runtime.h>

#define B 8
#define N 4096
#define NITER 4
#define TPB 256            // 4 waves/block
#define NCG 128            // colgroups: 32 cols x 4B = one exclusive 128B line/row
#define NBS 16             // b-slices
#define NBLK (NCG * NBS)   // 2048 blocks = 8 blocks/CU -> 32 waves/CU (max occupancy)
#define COLS 32
#define BSLEN (N / NBS)    // 256 rows per slice

// One diffusion iteration, partial over a b-slice.
// ROUND-15 COUNTERS (fused diagnostic): VALUBusy 10%, hbm 10%, 44us/iter vs
// 3.4us VALU floor -> pure latency-bound at 16 waves/CU + unroll 4. Also:
// cooperative launch costs ~90us fixed (dur_us 267 vs 176 rocprof; same gap
// r4/r9) -> multi-launch only. FETCH 133MB/4iter -> L3 retains P (~2x not 4x).
// FIX: 2048 small blocks -> 32 waves/CU (2x r12), unroll 8 (2x in-flight).
// Block = (colgroup, bslice): 32 cols x 256 rows; wave w: rows [w*64,+64);
// lane: cc2=l&15 -> cols c0+2*cc2+{0,1} (float2 = full 128B line per q-row),
// q=l>>4 -> 16 rows. Register: 16 prod + unroll-8 window ~= 50-64 VGPR,
// inside the 64-VGPR/8-wave envelope (r12 measured 36 at unroll 4).
__global__ __launch_bounds__(TPB) void step_kernel(
        const float* __restrict__ P,
        const float* __restrict__ srcT,   // [N][B] current pred, transposed
        float* __restrict__ partial)      // [NBS][N][B] partial products
{
    const int tid  = threadIdx.x;
    const int wave = tid >> 6;           // 0..3
    const int lane = tid & 63;
    const int cc2  = lane & 15;
    const int q    = lane >> 4;
    const int colgroup = blockIdx.x & (NCG - 1);
    const int bslice   = blockIdx.x >> 7;
    const int c0    = colgroup * COLS;
    const int rbase = bslice * BSLEN + wave * 64 + q * 16;

    float pr0[B], pr1[B];
#pragma unroll
    for (int i = 0; i < B; ++i) { pr0[i] = 1.0f; pr1[i] = 1.0f; }

    const float* Pp = P + (size_t)rbase * N + c0 + cc2 * 2;
    const float* sp = srcT + (size_t)rbase * B;

#pragma unroll 8
    for (int j = 0; j < 16; ++j) {
        const float2 p2 = *reinterpret_cast<const float2*>(Pp + (size_t)j * N);
        const float4 lo = *reinterpret_cast<const float4*>(sp + j * B);      // q-group-uniform, L2-hot
        const float4 hi = *reinterpret_cast<const float4*>(sp + j * B + 4);
        pr0[0] *= fmaf(-p2.x, lo.x, 1.0f);  pr1[0] *= fmaf(-p2.y, lo.x, 1.0f);
        pr0[1] *= fmaf(-p2.x, lo.y, 1.0f);  pr1[1] *= fmaf(-p2.y, lo.y, 1.0f);
        pr0[2] *= fmaf(-p2.x, lo.z, 1.0f);  pr1[2] *= fmaf(-p2.y, lo.z, 1.0f);
        pr0[3] *= fmaf(-p2.x, lo.w, 1.0f);  pr1[3] *= fmaf(-p2.y, lo.w, 1.0f);
        pr0[4] *= fmaf(-p2.x, hi.x, 1.0f);  pr1[4] *= fmaf(-p2.y, hi.x, 1.0f);
        pr0[5] *= fmaf(-p2.x, hi.y, 1.0f);  pr1[5] *= fmaf(-p2.y, hi.y, 1.0f);
        pr0[6] *= fmaf(-p2.x, hi.z, 1.0f);  pr1[6] *= fmaf(-p2.y, hi.z, 1.0f);
        pr0[7] *= fmaf(-p2.x, hi.w, 1.0f);  pr1[7] *= fmaf(-p2.y, hi.w, 1.0f);
    }

    // product across the 4 q-groups (lanes l, l^16, l^32, l^48 share cols)
#pragma unroll
    for (int i = 0; i < B; ++i) {
        pr0[i] *= __shfl_xor(pr0[i], 16);  pr0[i] *= __shfl_xor(pr0[i], 32);
        pr1[i] *= __shfl_xor(pr1[i], 16);  pr1[i] *= __shfl_xor(pr1[i], 32);
    }

    __shared__ float red[4][16][2][B];   // [wave][cc2][col-half][batch] = 4 KB
    if (lane < 16) {
#pragma unroll
        for (int i = 0; i < B; ++i) {
            red[wave][cc2][0][i] = pr0[i];
            red[wave][cc2][1][i] = pr1[i];
        }
    }
    __syncthreads();

    // all 256 threads: product across 4 waves, write partial coalesced
    const int col = tid >> 3;            // 0..31
    const int ri  = tid & 7;             // batch
    float r = 1.0f;
#pragma unroll
    for (int w = 0; w < 4; ++w) r *= red[w][col >> 1][col & 1][ri];
    partial[(size_t)bslice * (N * B) + (size_t)c0 * B + tid] = r;
}

// out/dstT = seed ? 1 : 1 - prod_s partial[s]  (16 slices, 2MB total read)
__global__ __launch_bounds__(256) void combine_kernel(
        const float* __restrict__ partial,
        const float* __restrict__ maskT,
        float* __restrict__ dstT,         // [N][B] next pred (if !last)
        float* __restrict__ out,          // [B][N] final (if last)
        int last)
{
    const int t = blockIdx.x * 256 + threadIdx.x;   // t = a*B + i
    float r = 1.0f;
#pragma unroll
    for (int s = 0; s < NBS; ++s) r *= partial[(size_t)s * (N * B) + t];
    float v = 1.0f - r;
    if (maskT[t] != 0.0f) v = 1.0f;
    if (!last) dstT[t] = v;                          // coalesced
    else out[(size_t)(t & 7) * N + (t >> 3)] = v;    // final row-major scatter (128KB)
}

// Transpose preds into [N][B] + scatter seed mask (maskT pre-zeroed by memset).
__global__ void prep_kernel(const float* __restrict__ preds,
                            const int* __restrict__ seed_idx, int nseeds,
                            float* __restrict__ predsT, float* __restrict__ maskT) {
    const int t = blockIdx.x * blockDim.x + threadIdx.x;   // t = i*N + n
    if (t < B * N) {
        const int i = t / N;
        const int n = t % N;
        predsT[(size_t)n * B + i] = preds[t];
    }
    if (t < nseeds) {
        const int b = seed_idx[2 * t + 0];
        const int n = seed_idx[2 * t + 1];
        maskT[(size_t)n * B + b] = 1.0f;
    }
}

extern "C" void kernel_launch(void* const* d_in, const int* in_sizes, int n_in,
                              void* d_out, int out_size, void* d_ws, size_t ws_size,
                              hipStream_t stream) {
    const float* preds    = (const float*)d_in[0];   // [B, N]
    const float* P        = (const float*)d_in[1];   // [N, N]
    const int*   seed_idx = (const int*)d_in[2];     // [NSEEDS, 2]
    const int nseeds = in_sizes[2] / 2;

    float* out     = (float*)d_out;                  // [B, N]
    float* bufA    = (float*)d_ws;                   // 128 KB each
    float* bufB    = bufA + (size_t)B * N;
    float* maskT   = bufB + (size_t)B * N;
    float* partial = maskT + (size_t)B * N;          // NBS*B*N floats = 2 MB

    hipMemsetAsync(maskT, 0, (size_t)B * N * sizeof(float), stream);
    prep_kernel<<<dim3((B * N) / 256), 256, 0, stream>>>(preds, seed_idx, nseeds, bufA, maskT);

    float* src = bufA;
    float* dst = bufB;
    for (int it = 0; it < NITER; ++it) {
        const int last = (it == NITER - 1);
        step_kernel<<<dim3(NBLK), dim3(TPB), 0, stream>>>(P, src, partial);
        combine_kernel<<<dim3((B * N) / 256), 256, 0, stream>>>(partial, maskT, dst, out, last);
        float* tmp = src; src = dst; dst = tmp;
    }
}

// Round 20
// 163.316 us; speedup vs baseline: 1.6362x; 1.0386x over previous
//
#include <hip/hip_runtime.h>

#define B 8
#define N 4096
#define NITER 4
#define TPB 256            // 4 waves/block
#define COLS 64            // 64 cols x 2B bf16 = one exclusive 128B line per row
#define NCG (N / COLS)     // 64 colgroups
#define NBS 32             // b-slices
#define NBLK (NCG * NBS)   // 2048 blocks = 8 blocks/CU
#define BSLEN (N / NBS)    // 128 rows per slice

typedef unsigned short u16;
typedef unsigned int   u32;

// ROUND-17 NULL RESULT: 32 waves/CU + unroll 8 == 16 waves/CU + unroll 4
// (169.6 vs 162.5us). Latency-hiding exonerated; with r15's counters
// (VALUBusy 10%, HBM 10%, P L3-resident) the wall is per-CU line-service /
// L3->L2 byte throughput. Only remaining lever: FEWER BYTES.
// => P converted to bf16 ONCE per call (ws is re-poisoned, so per-call),
//    steps stream 32MB/iter instead of 64MB. bf16 RN error: iter-1 output
//    perturbed ~3e-8 (~0.5ulp); final saturated outputs unchanged.

// P fp32 -> bf16 (round-to-nearest-even). 8 elts/thread, 16B in / 16B out.
__global__ __launch_bounds__(256) void convert_kernel(const float* __restrict__ P,
                                                      u32* __restrict__ Pbf /* as uint4-packed */) {
    const size_t t = (size_t)blockIdx.x * 256 + threadIdx.x;
    const float4* src = reinterpret_cast<const float4*>(P) + t * 2;
    const float4 a = src[0];
    const float4 b = src[1];
    const float v[8] = {a.x, a.y, a.z, a.w, b.x, b.y, b.z, b.w};
    u32 o[8];
#pragma unroll
    for (int k = 0; k < 8; ++k) {
        const u32 u = __float_as_uint(v[k]);
        o[k] = (u + 0x7FFFu + ((u >> 16) & 1u)) >> 16;   // RN-even bf16
    }
    uint4 w;
    w.x = o[0] | (o[1] << 16);
    w.y = o[2] | (o[3] << 16);
    w.z = o[4] | (o[5] << 16);
    w.w = o[6] | (o[7] << 16);
    reinterpret_cast<uint4*>(Pbf)[t] = w;
}

// One diffusion iteration, partial over a b-slice.
// Block = (colgroup, bslice): 64 cols x 128 rows.
//   wave w: rows [w*32, +32); half-wave q=lane>>5: 16 rows; cc=lane&31 ->
//   col-pair c0+2*cc+{0,1} (u32 = 2 bf16 = 4B/lane; 32 lanes x 4B = full
//   128B line per half-wave request, exclusively owned by this block).
// Registers: 16 prod + unroll-4 window (~36) + addr ~= 60 VGPR.
__global__ __launch_bounds__(TPB) void step_kernel(
        const u16* __restrict__ Pbf,
        const float* __restrict__ srcT,   // [N][B] current pred, transposed
        float* __restrict__ partial)      // [NBS][N][B] partial products
{
    const int tid  = threadIdx.x;
    const int wave = tid >> 6;           // 0..3
    const int lane = tid & 63;
    const int cc   = lane & 31;          // col-pair index
    const int q    = lane >> 5;          // 0..1
    const int colgroup = blockIdx.x & (NCG - 1);
    const int bslice   = blockIdx.x >> 6;
    const int c0    = colgroup * COLS;
    const int rbase = bslice * BSLEN + wave * 32 + q * 16;

    float pr0[B], pr1[B];
#pragma unroll
    for (int i = 0; i < B; ++i) { pr0[i] = 1.0f; pr1[i] = 1.0f; }

    const u16*   Pp = Pbf + (size_t)rbase * N + c0 + cc * 2;
    const float* sp = srcT + (size_t)rbase * B;

#pragma unroll 4
    for (int j = 0; j < 16; ++j) {
        const u32 pp = *reinterpret_cast<const u32*>(Pp + (size_t)j * N);
        const float p0 = __uint_as_float((pp & 0x0000FFFFu) << 16);  // col c0+2cc
        const float p1 = __uint_as_float(pp & 0xFFFF0000u);          // col c0+2cc+1
        const float4 lo = *reinterpret_cast<const float4*>(sp + j * B);      // half-wave-uniform, L1-hot
        const float4 hi = *reinterpret_cast<const float4*>(sp + j * B + 4);
        pr0[0] *= fmaf(-p0, lo.x, 1.0f);  pr1[0] *= fmaf(-p1, lo.x, 1.0f);
        pr0[1] *= fmaf(-p0, lo.y, 1.0f);  pr1[1] *= fmaf(-p1, lo.y, 1.0f);
        pr0[2] *= fmaf(-p0, lo.z, 1.0f);  pr1[2] *= fmaf(-p1, lo.z, 1.0f);
        pr0[3] *= fmaf(-p0, lo.w, 1.0f);  pr1[3] *= fmaf(-p1, lo.w, 1.0f);
        pr0[4] *= fmaf(-p0, hi.x, 1.0f);  pr1[4] *= fmaf(-p1, hi.x, 1.0f);
        pr0[5] *= fmaf(-p0, hi.y, 1.0f);  pr1[5] *= fmaf(-p1, hi.y, 1.0f);
        pr0[6] *= fmaf(-p0, hi.z, 1.0f);  pr1[6] *= fmaf(-p1, hi.z, 1.0f);
        pr0[7] *= fmaf(-p0, hi.w, 1.0f);  pr1[7] *= fmaf(-p1, hi.w, 1.0f);
    }

    // product across the 2 half-wave row-groups (lanes l and l^32 share cols)
#pragma unroll
    for (int i = 0; i < B; ++i) {
        pr0[i] *= __shfl_xor(pr0[i], 32);
        pr1[i] *= __shfl_xor(pr1[i], 32);
    }

    __shared__ float red[4][32][2][B];   // [wave][col-pair][half][batch] = 8 KB
    if (lane < 32) {
#pragma unroll
        for (int i = 0; i < B; ++i) {
            red[wave][cc][0][i] = pr0[i];
            red[wave][cc][1][i] = pr1[i];
        }
    }
    __syncthreads();

    // 256 threads x 2 reps: product across 4 waves, write partial coalesced
#pragma unroll
    for (int rep = 0; rep < 2; ++rep) {
        const int idx = rep * 256 + tid;       // 0..511 = col*B + batch
        const int col = idx >> 3;
        const int ri  = idx & 7;
        const float r = red[0][col >> 1][col & 1][ri] * red[1][col >> 1][col & 1][ri]
                      * red[2][col >> 1][col & 1][ri] * red[3][col >> 1][col & 1][ri];
        partial[(size_t)bslice * (N * B) + (size_t)c0 * B + idx] = r;
    }
}

// out/dstT = seed ? 1 : 1 - prod_s partial[s]  (32 slices, 4MB read, L2-hot)
__global__ __launch_bounds__(256) void combine_kernel(
        const float* __restrict__ partial,
        const float* __restrict__ maskT,
        float* __restrict__ dstT,         // [N][B] next pred (if !last)
        float* __restrict__ out,          // [B][N] final (if last)
        int last)
{
    const int t = blockIdx.x * 256 + threadIdx.x;   // t = a*B + i
    float r = 1.0f;
#pragma unroll
    for (int s = 0; s < NBS; ++s) r *= partial[(size_t)s * (N * B) + t];
    float v = 1.0f - r;
    if (maskT[t] != 0.0f) v = 1.0f;
    if (!last) dstT[t] = v;                          // coalesced
    else out[(size_t)(t & 7) * N + (t >> 3)] = v;    // final row-major scatter (128KB)
}

// Transpose preds into [N][B] + scatter seed mask (maskT pre-zeroed by memset).
__global__ void prep_kernel(const float* __restrict__ preds,
                            const int* __restrict__ seed_idx, int nseeds,
                            float* __restrict__ predsT, float* __restrict__ maskT) {
    const int t = blockIdx.x * blockDim.x + threadIdx.x;   // t = i*N + n
    if (t < B * N) {
        const int i = t / N;
        const int n = t % N;
        predsT[(size_t)n * B + i] = preds[t];
    }
    if (t < nseeds) {
        const int b = seed_idx[2 * t + 0];
        const int n = seed_idx[2 * t + 1];
        maskT[(size_t)n * B + b] = 1.0f;
    }
}

extern "C" void kernel_launch(void* const* d_in, const int* in_sizes, int n_in,
                              void* d_out, int out_size, void* d_ws, size_t ws_size,
                              hipStream_t stream) {
    const float* preds    = (const float*)d_in[0];   // [B, N]
    const float* P        = (const float*)d_in[1];   // [N, N]
    const int*   seed_idx = (const int*)d_in[2];     // [NSEEDS, 2]
    const int nseeds = in_sizes[2] / 2;

    float* out     = (float*)d_out;                  // [B, N]
    float* bufA    = (float*)d_ws;                   // 128 KB each
    float* bufB    = bufA + (size_t)B * N;
    float* maskT   = bufB + (size_t)B * N;
    float* partial = maskT + (size_t)B * N;          // NBS*B*N floats = 4 MB
    u16*   Pbf     = (u16*)(partial + (size_t)NBS * B * N);   // 32 MB (ws re-poisoned -> rebuild per call)

    hipMemsetAsync(maskT, 0, (size_t)B * N * sizeof(float), stream);
    convert_kernel<<<dim3((N * (size_t)N) / (256 * 8)), 256, 0, stream>>>(P, (u32*)Pbf);
    prep_kernel<<<dim3((B * N) / 256), 256, 0, stream>>>(preds, seed_idx, nseeds, bufA, maskT);

    float* src = bufA;
    float* dst = bufB;
    for (int it = 0; it < NITER; ++it) {
        const int last = (it == NITER - 1);
        step_kernel<<<dim3(NBLK), dim3(TPB), 0, stream>>>(Pbf, src, partial);
        combine_kernel<<<dim3((B * N) / 256), 256, 0, stream>>>(partial, maskT, dst, out, last);
        float* tmp = src; src = dst; dst = tmp;
    }
}

// Round 22
// 161.643 us; speedup vs baseline: 1.6532x; 1.0103x over previous
//
#include <hip/hip_runtime.h>

#define B 8
#define N 4096
#define NITER 4
#define TPB 256
#define NBS 16             // b-slices, shared by all steps; partial = [NBS][N][B]
#define BSLEN (N / NBS)    // 256 rows per slice

// step1 (fp32 P): 32 cols x 4B = one exclusive 128B line per row
#define COLS1 32
#define NCG1 (N / COLS1)   // 128
#define NBLK1 (NCG1 * NBS) // 2048
// stepN (bf16 P): 64 cols x 2B = one exclusive 128B line per row
#define COLS2 64
#define NCG2 (N / COLS2)   // 64
#define NBLK2 (NCG2 * NBS) // 1024

typedef unsigned short u16;
typedef unsigned int   u32;

// SESSION EVIDENCE: occupancy x2 (r17), ILP x2 (r17), 128B-exclusive lines
// (r12), bytes/2 (r20) -> ALL null; total pinned ~162-170us. Steps are not
// BW-bound; remaining addressable cost is whole dispatches. This round:
// (1) fuse fp32->bf16 convert INTO step1 (deletes a ~15us dispatch);
// (2) bitwise fixed-point skip: combine_k records whether pred_k != pred_{k-1};
//     if equal, iteration k+1 is the identity (deterministic map) -> step
//     exits immediately, combine copies. Runtime-verified, input-adaptive.

// Iteration 1: fp32 P in, partials out, bf16 P out (RNE) for iters 2..4.
__global__ __launch_bounds__(TPB) void step1_kernel(
        const float* __restrict__ P,
        const float* __restrict__ srcT,   // [N][B]
        float* __restrict__ partial,      // [NBS][N][B]
        u32* __restrict__ Pbf32)          // bf16 P as u32 pairs, row stride N/2
{
    const int tid  = threadIdx.x;
    const int wave = tid >> 6;           // 0..3
    const int lane = tid & 63;
    const int cc2  = lane & 15;          // col-pair
    const int q    = lane >> 4;          // 0..3 -> 16 rows each
    const int colgroup = blockIdx.x & (NCG1 - 1);
    const int bslice   = blockIdx.x >> 7;
    const int c0    = colgroup * COLS1;
    const int rbase = bslice * BSLEN + wave * 64 + q * 16;

    float pr0[B], pr1[B];
#pragma unroll
    for (int i = 0; i < B; ++i) { pr0[i] = 1.0f; pr1[i] = 1.0f; }

    const float* Pp = P + (size_t)rbase * N + c0 + cc2 * 2;
    const float* sp = srcT + (size_t)rbase * B;
    u32* Pw = Pbf32 + (size_t)rbase * (N / 2) + (c0 >> 1) + cc2;

#pragma unroll 4
    for (int j = 0; j < 16; ++j) {
        const float2 p2 = *reinterpret_cast<const float2*>(Pp + (size_t)j * N);
        const float4 lo = *reinterpret_cast<const float4*>(sp + j * B);
        const float4 hi = *reinterpret_cast<const float4*>(sp + j * B + 4);
        const u32 ux = __float_as_uint(p2.x), uy = __float_as_uint(p2.y);
        Pw[(size_t)j * (N / 2)] = ((ux + 0x7FFFu + ((ux >> 16) & 1u)) >> 16)
                                | (((uy + 0x7FFFu + ((uy >> 16) & 1u)) >> 16) << 16);
        pr0[0] *= fmaf(-p2.x, lo.x, 1.0f);  pr1[0] *= fmaf(-p2.y, lo.x, 1.0f);
        pr0[1] *= fmaf(-p2.x, lo.y, 1.0f);  pr1[1] *= fmaf(-p2.y, lo.y, 1.0f);
        pr0[2] *= fmaf(-p2.x, lo.z, 1.0f);  pr1[2] *= fmaf(-p2.y, lo.z, 1.0f);
        pr0[3] *= fmaf(-p2.x, lo.w, 1.0f);  pr1[3] *= fmaf(-p2.y, lo.w, 1.0f);
        pr0[4] *= fmaf(-p2.x, hi.x, 1.0f);  pr1[4] *= fmaf(-p2.y, hi.x, 1.0f);
        pr0[5] *= fmaf(-p2.x, hi.y, 1.0f);  pr1[5] *= fmaf(-p2.y, hi.y, 1.0f);
        pr0[6] *= fmaf(-p2.x, hi.z, 1.0f);  pr1[6] *= fmaf(-p2.y, hi.z, 1.0f);
        pr0[7] *= fmaf(-p2.x, hi.w, 1.0f);  pr1[7] *= fmaf(-p2.y, hi.w, 1.0f);
    }

#pragma unroll
    for (int i = 0; i < B; ++i) {
        pr0[i] *= __shfl_xor(pr0[i], 16);  pr0[i] *= __shfl_xor(pr0[i], 32);
        pr1[i] *= __shfl_xor(pr1[i], 16);  pr1[i] *= __shfl_xor(pr1[i], 32);
    }

    __shared__ float red[4][16][2][B];   // 4 KB
    if (lane < 16) {
#pragma unroll
        for (int i = 0; i < B; ++i) { red[wave][cc2][0][i] = pr0[i]; red[wave][cc2][1][i] = pr1[i]; }
    }
    __syncthreads();

    const int col = tid >> 3;            // 0..31
    const int ri  = tid & 7;
    const float r = red[0][col >> 1][col & 1][ri] * red[1][col >> 1][col & 1][ri]
                  * red[2][col >> 1][col & 1][ri] * red[3][col >> 1][col & 1][ri];
    partial[(size_t)bslice * (N * B) + (size_t)c0 * B + tid] = r;
}

// Iterations 2..4: bf16 P. Skips all work if previous iteration was a fixed point.
__global__ __launch_bounds__(TPB) void stepN_kernel(
        const u16* __restrict__ Pbf,
        const float* __restrict__ srcT,
        float* __restrict__ partial,
        const int* __restrict__ flags, int it)
{
    if (flags[it - 1] == 0) return;      // converged: this iteration is identity

    const int tid  = threadIdx.x;
    const int wave = tid >> 6;
    const int lane = tid & 63;
    const int cc   = lane & 31;          // col-pair
    const int q    = lane >> 5;          // 0..1 -> 32 rows each
    const int colgroup = blockIdx.x & (NCG2 - 1);
    const int bslice   = blockIdx.x >> 6;
    const int c0    = colgroup * COLS2;
    const int rbase = bslice * BSLEN + wave * 64 + q * 32;

    float pr0[B], pr1[B];
#pragma unroll
    for (int i = 0; i < B; ++i) { pr0[i] = 1.0f; pr1[i] = 1.0f; }

    const u16*   Pp = Pbf + (size_t)rbase * N + c0 + cc * 2;
    const float* sp = srcT + (size_t)rbase * B;

#pragma unroll 4
    for (int j = 0; j < 32; ++j) {
        const u32 pp = *reinterpret_cast<const u32*>(Pp + (size_t)j * N);
        const float p0 = __uint_as_float((pp & 0x0000FFFFu) << 16);
        const float p1 = __uint_as_float(pp & 0xFFFF0000u);
        const float4 lo = *reinterpret_cast<const float4*>(sp + j * B);
        const float4 hi = *reinterpret_cast<const float4*>(sp + j * B + 4);
        pr0[0] *= fmaf(-p0, lo.x, 1.0f);  pr1[0] *= fmaf(-p1, lo.x, 1.0f);
        pr0[1] *= fmaf(-p0, lo.y, 1.0f);  pr1[1] *= fmaf(-p1, lo.y, 1.0f);
        pr0[2] *= fmaf(-p0, lo.z, 1.0f);  pr1[2] *= fmaf(-p1, lo.z, 1.0f);
        pr0[3] *= fmaf(-p0, lo.w, 1.0f);  pr1[3] *= fmaf(-p1, lo.w, 1.0f);
        pr0[4] *= fmaf(-p0, hi.x, 1.0f);  pr1[4] *= fmaf(-p1, hi.x, 1.0f);
        pr0[5] *= fmaf(-p0, hi.y, 1.0f);  pr1[5] *= fmaf(-p1, hi.y, 1.0f);
        pr0[6] *= fmaf(-p0, hi.z, 1.0f);  pr1[6] *= fmaf(-p1, hi.z, 1.0f);
        pr0[7] *= fmaf(-p0, hi.w, 1.0f);  pr1[7] *= fmaf(-p1, hi.w, 1.0f);
    }

#pragma unroll
    for (int i = 0; i < B; ++i) {
        pr0[i] *= __shfl_xor(pr0[i], 32);
        pr1[i] *= __shfl_xor(pr1[i], 32);
    }

    __shared__ float red[4][32][2][B];   // 8 KB
    if (lane < 32) {
#pragma unroll
        for (int i = 0; i < B; ++i) { red[wave][cc][0][i] = pr0[i]; red[wave][cc][1][i] = pr1[i]; }
    }
    __syncthreads();

#pragma unroll
    for (int rep = 0; rep < 2; ++rep) {
        const int idx = rep * 256 + tid;       // 0..511 = col*B + batch
        const int col = idx >> 3;
        const int ri  = idx & 7;
        const float r = red[0][col >> 1][col & 1][ri] * red[1][col >> 1][col & 1][ri]
                      * red[2][col >> 1][col & 1][ri] * red[3][col >> 1][col & 1][ri];
        partial[(size_t)bslice * (N * B) + (size_t)c0 * B + idx] = r;
    }
}

// dst = seed ? 1 : 1 - prod_s partial[s]; records fixed-point flag (bitwise).
__global__ __launch_bounds__(256) void combine_kernel(
        const float* __restrict__ partial,
        const float* __restrict__ maskT,
        const float* __restrict__ srcT,
        float* __restrict__ dstT,
        float* __restrict__ out,
        int last, int* __restrict__ flags, int it)
{
    const int t = blockIdx.x * 256 + threadIdx.x;   // t = a*B + i

    if (it > 0 && flags[it - 1] == 0) {              // converged: identity copy
        const float s = srcT[t];
        if (!last) dstT[t] = s;
        else       out[(size_t)(t & 7) * N + (t >> 3)] = s;
        return;
    }

    float r = 1.0f;
#pragma unroll
    for (int s = 0; s < NBS; ++s) r *= partial[(size_t)s * (N * B) + t];
    float v = 1.0f - r;
    if (maskT[t] != 0.0f) v = 1.0f;
    if (!last) {
        dstT[t] = v;
        if (__float_as_uint(v) != __float_as_uint(srcT[t])) flags[it] = 1;  // racy same-value store: fine
    } else {
        out[(size_t)(t & 7) * N + (t >> 3)] = v;
    }
}

// Transpose preds into [N][B] + scatter seed mask (maskT+flags pre-zeroed).
__global__ void prep_kernel(const float* __restrict__ preds,
                            const int* __restrict__ seed_idx, int nseeds,
                            float* __restrict__ predsT, float* __restrict__ maskT) {
    const int t = blockIdx.x * blockDim.x + threadIdx.x;   // t = i*N + n
    if (t < B * N) {
        const int i = t / N;
        const int n = t % N;
        predsT[(size_t)n * B + i] = preds[t];
    }
    if (t < nseeds) {
        const int b = seed_idx[2 * t + 0];
        const int n = seed_idx[2 * t + 1];
        maskT[(size_t)n * B + b] = 1.0f;
    }
}

extern "C" void kernel_launch(void* const* d_in, const int* in_sizes, int n_in,
                              void* d_out, int out_size, void* d_ws, size_t ws_size,
                              hipStream_t stream) {
    const float* preds    = (const float*)d_in[0];   // [B, N]
    const float* P        = (const float*)d_in[1];   // [N, N]
    const int*   seed_idx = (const int*)d_in[2];     // [NSEEDS, 2]
    const int nseeds = in_sizes[2] / 2;

    float* out     = (float*)d_out;                  // [B, N]
    float* bufA    = (float*)d_ws;                   // 128 KB each
    float* bufB    = bufA + (size_t)B * N;
    float* maskT   = bufB + (size_t)B * N;
    int*   flags   = (int*)(maskT + (size_t)B * N);  // 16 ints, zeroed with maskT
    float* partial = (float*)(flags + 16);           // NBS*B*N floats = 2 MB
    u16*   Pbf     = (u16*)(partial + (size_t)NBS * B * N);   // 32 MB

    hipMemsetAsync(maskT, 0, (size_t)B * N * sizeof(float) + 16 * sizeof(int), stream);
    prep_kernel<<<dim3((B * N) / 256), 256, 0, stream>>>(preds, seed_idx, nseeds, bufA, maskT);

    // it 0: fp32 P, emits bf16 P
    step1_kernel<<<dim3(NBLK1), dim3(TPB), 0, stream>>>(P, bufA, partial, (u32*)Pbf);
    combine_kernel<<<dim3((B * N) / 256), 256, 0, stream>>>(partial, maskT, bufA, bufB, out, 0, flags, 0);

    float* src = bufB;
    float* dst = bufA;
    for (int it = 1; it < NITER; ++it) {
        const int last = (it == NITER - 1);
        stepN_kernel<<<dim3(NBLK2), dim3(TPB), 0, stream>>>(Pbf, src, partial, flags, it);
        combine_kernel<<<dim3((B * N) / 256), 256, 0, stream>>>(partial, maskT, src, dst, out, last, flags, it);
        float* tmp = src; src = dst; dst = tmp;
    }
}